// Round 4
// baseline (248.375 us; speedup 1.0000x reference)
//
#include <hip/hip_runtime.h>
#include <math.h>

// Problem constants: B=2, S=2048, U=1024, H=16, DK=64
#define B_NUM 2
#define S_LEN 2048
#define U_DIM 1024
#define H_NUM 16
#define DK 64
#define M_TOT (B_NUM * S_LEN)   // 4096

typedef __attribute__((ext_vector_type(8))) short bf8;   // 8 bf16 (MFMA A/B frag)
typedef __attribute__((ext_vector_type(4))) float f4;    // MFMA C/D frag

// float -> bf16 (round to nearest even), raw ushort bits
__device__ __forceinline__ unsigned short f2bf(float f) {
    union { float f; unsigned int u; } x; x.f = f;
    unsigned int r = x.u + 0x7fffu + ((x.u >> 16) & 1u);
    return (unsigned short)(r >> 16);
}

// packed f32x2 -> bf16x2 (hardware cvt; used in GEMM staging + attn P-pack)
__device__ __forceinline__ unsigned int pkbf(float a, float b) {
    unsigned int r;
    asm("v_cvt_pk_bf16_f32 %0, %1, %2" : "=v"(r) : "v"(a), "v"(b));
    return r;
}
__device__ __forceinline__ uint4 pack8(float4 u, float4 v) {
    return (uint4){pkbf(u.x, u.y), pkbf(u.z, u.w), pkbf(v.x, v.y), pkbf(v.z, v.w)};
}

// async global->LDS, 16 B per lane; LDS dest = wave-uniform base + lane*16
__device__ __forceinline__ void gl2lds16(const void* g, void* l) {
    __builtin_amdgcn_global_load_lds(
        (const __attribute__((address_space(1))) unsigned int*)g,
        (__attribute__((address_space(3))) unsigned int*)l, 16, 0, 0);
}

// ---------------------------------------------------------------------------
// bf16 MFMA GEMM, register-prefetch + LDS DOUBLE BUFFER: one barrier per
// K-iter. C[M,N] = A[M,K] @ W[N,K]^T + bias, *scale. 128x128 tile, BK=32.
// R4: NO SEPARATE fp32->bf16 CONVERSION PASS. A (if AF32) and W are read
// as raw fp32 and packed to bf16 with v_cvt_pk_bf16_f32 at the ds_write
// point (the old wait point).  VALUBusy was 11.7% -> plenty of headroom;
// deletes a whole kernel launch + 32 MB of HBM round-trip.
// LDS tile DECLARED IN THE KERNEL and passed in (two inlined template
// instantiations would otherwise each get their own static __shared__:
// observed LDS_Block_Size=65536 -> 2 blocks/CU, fixed in R2).
// OMODE: 0 = bf16 [M,U] row-major; 1 = f32 [M,U]; 2 = bf16 V-TRANSPOSED
// layout VT[((b*H+h)*64+d)*S + s]  (fuses the old transpose_v kernel).
// ---------------------------------------------------------------------------
struct GemmLds {
    unsigned short As[2][128][32];
    unsigned short Bs[2][128][32];
};

template <int OMODE, bool AF32>
__device__ __forceinline__ void gemm_core(
    GemmLds& S,
    const void* __restrict__ Av, const float* __restrict__ Wf,
    const float* __restrict__ bias, void* __restrict__ Cv, float scale,
    int bx, int by)
{
    const int tid = threadIdx.x;
    const int w = tid >> 6, lane = tid & 63;
    const int quad = lane >> 4, cid = lane & 15;
    const int wy = w >> 1, wx = w & 1;
    const int m0 = by * 128, n0 = bx * 128;

    const int row_s = tid >> 1;                  // 0..127
    const int sp = tid & 1;                      // 16-elem half
    const int rr = (row_s >> 2) & 3;
    const int p0 = (2 * sp + rr) & 3;            // phys 16B slot of seg 2sp
    const int p1 = (2 * sp + 1 + rr) & 3;

    const unsigned short* gA =
        (const unsigned short*)Av + (size_t)(m0 + row_s) * U_DIM + 16 * sp;
    const float* gAf =
        (const float*)Av + (size_t)(m0 + row_s) * U_DIM + 16 * sp;
    const float* gBf = Wf + (size_t)(n0 + row_s) * U_DIM + 16 * sp;

    uint4 a0, a1;
    float4 fa0, fa1, fa2, fa3, fb0, fb1, fb2, fb3;
#define GPF(k0_) do {                                       \
        if constexpr (AF32) {                               \
            fa0 = *(const float4*)(gAf + (k0_));            \
            fa1 = *(const float4*)(gAf + (k0_) + 4);        \
            fa2 = *(const float4*)(gAf + (k0_) + 8);        \
            fa3 = *(const float4*)(gAf + (k0_) + 12);       \
        } else {                                            \
            a0 = *(const uint4*)(gA + (k0_));               \
            a1 = *(const uint4*)(gA + (k0_) + 8);           \
        }                                                   \
        fb0 = *(const float4*)(gBf + (k0_));                \
        fb1 = *(const float4*)(gBf + (k0_) + 4);            \
        fb2 = *(const float4*)(gBf + (k0_) + 8);            \
        fb3 = *(const float4*)(gBf + (k0_) + 12);           \
    } while (0)

    // convert (if needed) + swizzled ds_write of the staged tile
#define STORE(buf_) do {                                    \
        uint4 ta0, ta1;                                     \
        if constexpr (AF32) {                               \
            ta0 = pack8(fa0, fa1); ta1 = pack8(fa2, fa3);   \
        } else { ta0 = a0; ta1 = a1; }                      \
        uint4 tb0 = pack8(fb0, fb1), tb1 = pack8(fb2, fb3); \
        *(uint4*)&S.As[buf_][row_s][p0 * 8] = ta0;          \
        *(uint4*)&S.As[buf_][row_s][p1 * 8] = ta1;          \
        *(uint4*)&S.Bs[buf_][row_s][p0 * 8] = tb0;          \
        *(uint4*)&S.Bs[buf_][row_s][p1 * 8] = tb1;          \
    } while (0)

    f4 acc[4][4] = {};

    // prologue: tile 0 -> buf 0; tile 1 in regs
    GPF(0);
    STORE(0);
    GPF(32);
    __syncthreads();

#pragma unroll 2
    for (int k0 = 0; k0 < U_DIM; k0 += 32) {
        const int cur = (k0 >> 5) & 1;
        if (k0 + 32 < U_DIM) {
            STORE(cur ^ 1);
            if (k0 + 64 < U_DIM) GPF(k0 + 64);   // in flight across compute
        }

        bf8 af[4], bfr[4];
#pragma unroll
        for (int mt = 0; mt < 4; ++mt) {
            int row = wy * 64 + mt * 16 + cid;
            int seg = (quad + (row >> 2)) & 3;
            af[mt] = *(const bf8*)&S.As[cur][row][seg * 8];
        }
#pragma unroll
        for (int nt = 0; nt < 4; ++nt) {
            int row = wx * 64 + nt * 16 + cid;
            int seg = (quad + (row >> 2)) & 3;
            bfr[nt] = *(const bf8*)&S.Bs[cur][row][seg * 8];
        }
#pragma unroll
        for (int mt = 0; mt < 4; ++mt)
#pragma unroll
            for (int nt = 0; nt < 4; ++nt)
                acc[mt][nt] = __builtin_amdgcn_mfma_f32_16x16x32_bf16(
                    af[mt], bfr[nt], acc[mt][nt], 0, 0, 0);
        __syncthreads();   // reads of cur done; writes of nxt visible
    }
#undef GPF
#undef STORE

#pragma unroll
    for (int nt = 0; nt < 4; ++nt) {
        int col = n0 + wx * 64 + nt * 16 + cid;
        float bv = bias[col];
#pragma unroll
        for (int mt = 0; mt < 4; ++mt) {
            int rowb = m0 + wy * 64 + mt * 16 + quad * 4;
#pragma unroll
            for (int i = 0; i < 4; ++i) {
                float v = (acc[mt][nt][i] + bv) * scale;
                if constexpr (OMODE == 0) {
                    ((unsigned short*)Cv)[(size_t)(rowb + i) * U_DIM + col] = f2bf(v);
                } else if constexpr (OMODE == 1) {
                    ((float*)Cv)[(size_t)(rowb + i) * U_DIM + col] = v;
                } else {
                    // V output written directly in transposed layout:
                    // [b, s, h*64+d] -> VT[((b*H+h)*64+d)*S + s]
                    int bb = rowb >> 11;
                    int ss = (rowb & (S_LEN - 1)) + i;
                    size_t idx = ((size_t)(bb * H_NUM + (col >> 6)) * DK + (col & 63))
                                 * S_LEN + ss;
                    ((unsigned short*)Cv)[idx] = f2bf(v);
                }
            }
        }
    }
}

struct QkvArgs {
    const void* A[3];        // fp32 activations (query/key/value)
    const float* W[3];       // fp32 weights
    const float* bias[3];
    unsigned short* C[3];
    float scale[3];
};

// XCD remap (R2, verified): each XCD owns 4 m-tiles x 8 n-tiles per z-slice.
__global__ __launch_bounds__(256, 3) void gemm_qkv(QkvArgs a) {
    __shared__ GemmLds S;
    const int L = (int)blockIdx.x + 8 * ((int)blockIdx.y + 32 * (int)blockIdx.z);
    const int xcd = L & 7, j = L >> 3;       // j in [0,96)
    const int z = j >> 5, r = j & 31;        // r in [0,32)
    const int by = xcd * 4 + (r & 3);
    const int bx = r >> 2;
    if (z == 2)
        gemm_core<2, true>(S, a.A[2], a.W[2], a.bias[2], a.C[2], a.scale[2], bx, by);
    else
        gemm_core<0, true>(S, a.A[z], a.W[z], a.bias[z], a.C[z], a.scale[z], bx, by);
}

__global__ __launch_bounds__(256, 3) void gemm_obf(
    const unsigned short* __restrict__ A, const float* __restrict__ W,
    const float* __restrict__ bias, float* __restrict__ C) {
    __shared__ GemmLds S;
    const int L = (int)blockIdx.x + 8 * (int)blockIdx.y;
    const int xcd = L & 7, j = L >> 3;       // j in [0,32)
    const int by = xcd * 4 + (j & 3);
    const int bx = j >> 2;
    gemm_core<1, false>(S, A, W, bias, C, 1.0f, bx, by);
}

// ---------------------------------------------------------------------------
// MFMA flash attention, R3 structure (verified): SWAPPED QK^T + IN-REGISTER
// P REDISTRIBUTION (cvt_pk + permlane32_swap + ds_swizzle), no-max softmax
// (exp2; log2e folded into Q-GEMM scale), 32 KB LDS -> 4 blocks/CU, whole
// 1024-block grid resident.  XCD-grouped remap (R2: FETCH 63->12 MB).
// ---------------------------------------------------------------------------
__global__ __launch_bounds__(256, 4) void attn_mfma(
    const unsigned short* __restrict__ Q, const unsigned short* __restrict__ K,
    const unsigned short* __restrict__ VT, unsigned short* __restrict__ O)
{
    __shared__ __align__(16) unsigned short Ks[128][64];   // also Q staging alias
    __shared__ __align__(16) unsigned short Vs[64][128];

    // ---- XCD-grouping remap (linear-ID % 8 = XCD round-robin) ----
    const int L = (int)blockIdx.x + 32 * ((int)blockIdx.y + 16 * (int)blockIdx.z);
    const int xcd = L & 7;
    const int j   = L >> 3;          // 0..127 within this XCD
    const int gl  = j & 3;           // which of this XCD's 4 (b,h) groups
    const int i   = j >> 2;          // 0..31
    const int hb  = (xcd << 2) | gl; // 0..31
    const int h = hb & 15, b = hb >> 4;
    // balanced qt permutation: {perm[x],perm[x+8],perm[x+16],perm[x+24]}
    // sums to 62 k-tiles for every x (CU-level static balance).
    const int px = i & 7, pk = i >> 3;
    const int qt = (pk == 0) ? 31 - px : (pk == 1) ? 16 + px
                 : (pk == 2) ? 15 - px : px;

    const int q0 = qt * 64;
    const int tid = threadIdx.x, w = tid >> 6, lane = tid & 63;
    const int quad = lane >> 4, cid = lane & 15;

#define KFRAG(r, s) (*(const bf8*)&Ks[r][(((s) ^ ((r) & 7)) * 8)])
#define VFRAG(r, s) (*(const bf8*)&Vs[r][(((((s) & 8) | (((s) ^ (r)) & 7))) * 8)])

    // ---- stage Q once via gl2lds16 into the Ks alias (XOR swizzle) ----
    unsigned short (*QsA)[64] = (unsigned short (*)[64])&Ks[0][0];
    const int srow8 = lane >> 3;                 // 0..7
    const int sw = ((lane & 7) ^ srow8) * 8;     // swizzled source col
    {
        const unsigned short* qg =
            Q + ((size_t)b * S_LEN + q0 + w * 16 + srow8) * U_DIM + h * DK + sw;
        gl2lds16(qg, &QsA[w * 16][0]);
        gl2lds16(qg + 8 * U_DIM, &QsA[w * 16 + 8][0]);
    }
    __syncthreads();
    const bf8 qfa = *(const bf8*)&QsA[w * 16 + cid][(((quad) ^ (cid & 7)) * 8)];
    const bf8 qfb = *(const bf8*)&QsA[w * 16 + cid][((((quad + 4)) ^ (cid & 7)) * 8)];
    // Ks overwrites happen only after iter-0's two __syncthreads -> safe.

    // ---- staging addressing ----
    const unsigned short* kgl =
        K + ((size_t)b * S_LEN + w * 32 + srow8) * U_DIM + h * DK + (lane & 7) * 8;
    const int vr0 = lane >> 4;
    const int s16 = lane & 15;
    const unsigned short* vgl =
        VT + ((size_t)(b * H_NUM + h) * DK + w * 16 + vr0) * S_LEN + s16 * 8;
    const int spE = (((s16 & 8) | ((s16 ^ vr0) & 7))) * 8;        // c even
    const int spO = (((s16 & 8) | ((s16 ^ (vr0 + 4)) & 7))) * 8;  // c odd
    const int ksw = ((lane & 7) ^ srow8) * 8;                     // K dest seg

    // named staging registers (NOT arrays — must stay in VGPRs)
    uint4 kr0, kr1, kr2, kr3, vq0, vq1, vq2, vq3;
#define PREFETCH(kt_) do {                                                    \
        const unsigned short* kp_ = kgl + (size_t)(kt_) * 128 * U_DIM;        \
        kr0 = *(const uint4*)(kp_);                                           \
        kr1 = *(const uint4*)(kp_ + (size_t)8 * U_DIM);                       \
        kr2 = *(const uint4*)(kp_ + (size_t)16 * U_DIM);                      \
        kr3 = *(const uint4*)(kp_ + (size_t)24 * U_DIM);                      \
        const unsigned short* vp_ = vgl + (kt_) * 128;                        \
        vq0 = *(const uint4*)(vp_);                                           \
        vq1 = *(const uint4*)(vp_ + (size_t)4 * S_LEN);                       \
        vq2 = *(const uint4*)(vp_ + (size_t)8 * S_LEN);                       \
        vq3 = *(const uint4*)(vp_ + (size_t)12 * S_LEN);                      \
    } while (0)

    f4 o[4] = {};
    float l_p = 0.0f;                 // per-lane partial row sum (q = cid)
    const int qrow = q0 + w * 16 + cid;

    const int nkt = (qt >> 1) + 1;   // 128-key tiles (even qt: top half masked)
    PREFETCH(0);

    for (int kt = 0; kt < nkt; ++kt) {
        __syncthreads();            // prev-iter frag reads done; LDS writable
        *(uint4*)&Ks[w * 32 + 0  + srow8][ksw] = kr0;
        *(uint4*)&Ks[w * 32 + 8  + srow8][ksw] = kr1;
        *(uint4*)&Ks[w * 32 + 16 + srow8][ksw] = kr2;
        *(uint4*)&Ks[w * 32 + 24 + srow8][ksw] = kr3;
        *(uint4*)&Vs[w * 16 + 0  + vr0][spE] = vq0;
        *(uint4*)&Vs[w * 16 + 4  + vr0][spO] = vq1;
        *(uint4*)&Vs[w * 16 + 8  + vr0][spE] = vq2;
        *(uint4*)&Vs[w * 16 + 12 + vr0][spO] = vq3;
        __syncthreads();            // tiles visible
        if (kt + 1 < nkt) PREFETCH(kt + 1);   // in flight across compute

        // ---- S^T = K Q^T over 128 keys (swapped operands).  Lane holds
        //      S[key = 16t + 4*quad + i][q = cid].  Pre-scaled by
        //      log2(e)/sqrt(DK) in the Q GEMM -> softmax uses exp2. ----
        f4 sc[8];
#pragma unroll
        for (int t = 0; t < 8; ++t) {
            int r = t * 16 + cid;
            f4 a = {};
            a = __builtin_amdgcn_mfma_f32_16x16x32_bf16(KFRAG(r, quad), qfa, a, 0, 0, 0);
            a = __builtin_amdgcn_mfma_f32_16x16x32_bf16(KFRAG(r, quad + 4), qfb, a, 0, 0, 0);
            sc[t] = a;
        }

        // ---- causal mask (last tile only; covers even-qt dead half) ----
        if (kt == nkt - 1) {
#pragma unroll
            for (int t = 0; t < 8; ++t) {
#pragma unroll
                for (int i2 = 0; i2 < 4; ++i2) {
                    int key = kt * 128 + t * 16 + quad * 4 + i2;
                    if (key > qrow) sc[t][i2] = -1e30f;
                }
            }
        }

        // ---- exp2 + per-lane partial l (single scalar: all keys, q=cid) ----
#pragma unroll
        for (int t = 0; t < 8; ++t) {
#pragma unroll
            for (int i2 = 0; i2 < 4; ++i2) {
                float p = exp2f(sc[t][i2]);
                sc[t][i2] = p;
                l_p += p;
            }
        }

        // ---- pack P to bf16 pairs: r_[t] = keys {16t+4q+0,+1},
        //      r2_[t] = keys {16t+4q+2,+3} (q = this lane's quad) ----
        unsigned int r_[8], r2_[8];
#pragma unroll
        for (int t = 0; t < 8; ++t) {
            r_[t]  = pkbf(sc[t][0], sc[t][1]);
            r2_[t] = pkbf(sc[t][2], sc[t][3]);
        }

        // ---- route pairs to PV A-frags and accumulate PV ----
        const bool qodd = (quad & 1) != 0;
#pragma unroll
        for (int f = 0; f < 4; ++f) {
            unsigned int xa = r_[2 * f], ya = r_[2 * f + 1];
            asm("v_permlane32_swap_b32 %0, %1" : "+v"(xa), "+v"(ya));
            unsigned int xas = __builtin_amdgcn_ds_swizzle((int)xa, 0x401f);
            unsigned int yas = __builtin_amdgcn_ds_swizzle((int)ya, 0x401f);
            unsigned int xb = r2_[2 * f], yb = r2_[2 * f + 1];
            asm("v_permlane32_swap_b32 %0, %1" : "+v"(xb), "+v"(yb));
            unsigned int xbs = __builtin_amdgcn_ds_swizzle((int)xb, 0x401f);
            unsigned int ybs = __builtin_amdgcn_ds_swizzle((int)yb, 0x401f);
            unsigned int u0 = qodd ? yas : xa;
            unsigned int u1 = qodd ? ybs : xb;
            unsigned int u2 = qodd ? ya : xas;
            unsigned int u3 = qodd ? yb : xbs;
            union { uint4 u; bf8 v; } pf;
            pf.u = (uint4){u0, u1, u2, u3};
#pragma unroll
            for (int t = 0; t < 4; ++t) {
                int r = t * 16 + cid;
                o[t] = __builtin_amdgcn_mfma_f32_16x16x32_bf16(
                    pf.v, VFRAG(r, 4 * f + quad), o[t], 0, 0, 0);
            }
        }
    }
#undef PREFETCH
#undef KFRAG
#undef VFRAG

    // ---- epilogue: l reduce across quads (lanes sharing cid), then
    //      redistribute inv to the o-row owners, O/l -> bf16 [b,s,u] ----
    float l = l_p;
    l += __shfl_xor(l, 16);
    l += __shfl_xor(l, 32);
    const float inv = 1.0f / l;          // valid for q-row = cid (all lanes)
#pragma unroll
    for (int i2 = 0; i2 < 4; ++i2) {
        // o rows are q = quad*4+i2; fetch inv from the lane with that cid.
        float invi = __shfl(inv, (lane & 48) | (quad * 4 + i2));
        int rowg = q0 + w * 16 + quad * 4 + i2;
        size_t rbase = ((size_t)b * S_LEN + rowg) * U_DIM + h * DK;
#pragma unroll
        for (int t = 0; t < 4; ++t)
            O[rbase + t * 16 + cid] = f2bf(o[t][i2] * invi);
    }
}

// ---------------------------------------------------------------------------
// ws layout (bf16): qg|kg|vt|ao (8MB ea) = 32 MB total.
// (fp32->bf16 conversion pass deleted in R4: GEMMs read fp32 directly.)
// ---------------------------------------------------------------------------
extern "C" void kernel_launch(void* const* d_in, const int* in_sizes, int n_in,
                              void* d_out, int out_size, void* d_ws, size_t ws_size,
                              hipStream_t stream)
{
    const float* query = (const float*)d_in[0];
    const float* key   = (const float*)d_in[1];
    const float* value = (const float*)d_in[2];
    const float* Wq = (const float*)d_in[4];
    const float* bq = (const float*)d_in[5];
    const float* Wk = (const float*)d_in[6];
    const float* bk = (const float*)d_in[7];
    const float* Wv = (const float*)d_in[8];
    const float* bv = (const float*)d_in[9];
    const float* Wo = (const float*)d_in[10];
    const float* bo = (const float*)d_in[11];
    float* out = (float*)d_out;

    const size_t ACT = (size_t)M_TOT * U_DIM;

    unsigned short* qg = (unsigned short*)d_ws;
    unsigned short* kg = qg + ACT;
    unsigned short* vt = kg + ACT;
    unsigned short* ao = vt + ACT;

    // Q scale folds softmax's 1/sqrt(DK) AND log2(e) (attn uses exp2).
    QkvArgs ga;
    ga.A[0] = query; ga.W[0] = Wq; ga.bias[0] = bq; ga.C[0] = qg;
    ga.scale[0] = 0.125f * 1.44269504088896340736f;
    ga.A[1] = key;   ga.W[1] = Wk; ga.bias[1] = bk; ga.C[1] = kg; ga.scale[1] = 1.0f;
    ga.A[2] = value; ga.W[2] = Wv; ga.bias[2] = bv; ga.C[2] = vt; ga.scale[2] = 1.0f;
    gemm_qkv<<<dim3(U_DIM / 128, M_TOT / 128, 3), 256, 0, stream>>>(ga);

    attn_mfma<<<dim3(S_LEN / 64, H_NUM, B_NUM), 256, 0, stream>>>(qg, kg, vt, ao);

    gemm_obf<<<dim3(U_DIM / 128, M_TOT / 128), 256, 0, stream>>>(ao, Wo, bo, out);
}

// Round 5
// 224.904 us; speedup vs baseline: 1.1044x; 1.1044x over previous
//
#include <hip/hip_runtime.h>
#include <math.h>

// Problem constants: B=2, S=2048, U=1024, H=16, DK=64
#define B_NUM 2
#define S_LEN 2048
#define U_DIM 1024
#define H_NUM 16
#define DK 64
#define M_TOT (B_NUM * S_LEN)   // 4096

typedef __attribute__((ext_vector_type(8))) short bf8;   // 8 bf16 (MFMA A/B frag)
typedef __attribute__((ext_vector_type(4))) float f4;    // MFMA C/D frag

// float -> bf16 (round to nearest even), raw ushort bits
__device__ __forceinline__ unsigned short f2bf(float f) {
    union { float f; unsigned int u; } x; x.f = f;
    unsigned int r = x.u + 0x7fffu + ((x.u >> 16) & 1u);
    return (unsigned short)(r >> 16);
}

// packed f32x2 -> bf16x2 (hardware cvt; used in attn P-pack)
__device__ __forceinline__ unsigned int pkbf(float a, float b) {
    unsigned int r;
    asm("v_cvt_pk_bf16_f32 %0, %1, %2" : "=v"(r) : "v"(a), "v"(b));
    return r;
}

// async global->LDS, 16 B per lane; LDS dest = wave-uniform base + lane*16
__device__ __forceinline__ void gl2lds16(const void* g, void* l) {
    __builtin_amdgcn_global_load_lds(
        (const __attribute__((address_space(1))) unsigned int*)g,
        (__attribute__((address_space(3))) unsigned int*)l, 16, 0, 0);
}

// ---------------------------------------------------------------------------
// Bulk fp32 -> bf16 conversion. blockIdx.y selects one of 7 tensors.
// (R4 tried deleting this and reading fp32 in the GEMM: staging bytes
// doubled and gemm_qkv went 42.5 -> 77 us. The GEMM is staging-path-bound:
// ~2.1 us per staged KB per K-step. Restored.)
// ---------------------------------------------------------------------------
struct CvtArgs {
    const float* src[7];
    unsigned short* dst[7];
    int n[7];
};

__global__ __launch_bounds__(256) void convert_bf16(CvtArgs a)
{
    const int seg = blockIdx.y;
    const int i = (blockIdx.x * 256 + threadIdx.x) * 8;
    if (i >= a.n[seg]) return;
    const float* s = a.src[seg] + i;
    float4 v0 = *(const float4*)s;
    float4 v1 = *(const float4*)(s + 4);
    uint4 o = {pkbf(v0.x, v0.y), pkbf(v0.z, v0.w),
               pkbf(v1.x, v1.y), pkbf(v1.z, v1.w)};
    *(uint4*)(a.dst[seg] + i) = o;
}

// ---------------------------------------------------------------------------
// bf16 MFMA GEMM, R5: GLOBAL_LOAD_LDS staging (m97 structure).
// C[M,N] = A[M,K] @ W[N,K]^T + bias, *scale. 128x128 tile, BK=32, LDS dbuf.
// Staging is direct-to-LDS (no VGPR round-trip, no per-lane addr VALU in
// the loop): wave w stages rows 32w..32w+31 of A and B tiles; linear LDS
// dest (wave base + lane*16); the SOURCE column segment is inverse-rotated
// by rr=(row>>2)&3 so phys 16B slot s holds logical seg (s-rr)&3 -- the
// conflict-free read macros below are unchanged from R3.
// One barrier per K-iter; the compiler's vmcnt(0) drain before s_barrier
// makes all waves' cur-tile loads visible before any frag read.
// LDS struct passed in (two inlined instantiations would each get their
// own static __shared__: observed 65536 -> 2 blocks/CU, fixed R2).
// OMODE: 0 = bf16 [M,U]; 1 = f32 [M,U]; 2 = bf16 V-TRANSPOSED
// layout VT[((b*H+h)*64+d)*S + s]  (fuses the old transpose_v kernel).
// ---------------------------------------------------------------------------
struct GemmLds {
    unsigned short As[2][128][32];
    unsigned short Bs[2][128][32];
};

template <int OMODE>
__device__ __forceinline__ void gemm_core(
    GemmLds& S,
    const unsigned short* __restrict__ A, const unsigned short* __restrict__ W,
    const float* __restrict__ bias, void* __restrict__ Cv, float scale,
    int bx, int by)
{
    const int tid = threadIdx.x;
    const int w = tid >> 6, lane = tid & 63;
    const int quad = lane >> 4, cid = lane & 15;
    const int wy = w >> 1, wx = w & 1;
    const int m0 = by * 128, n0 = bx * 128;

    // staging addressing: lane l -> row 32w + (l>>2), phys slot s = l&3.
    // rr is identical for row and row+16 ((r>>2)&3 changes by 4).
    const int l2 = lane >> 2, s4 = lane & 3;
    const int ra = 32 * w + l2;
    const int rr = (ra >> 2) & 3;
    const int cseg = (((s4 + 4) - rr) & 3) * 8;   // bf16-elem source offset
    const unsigned short* gAs = A + (size_t)(m0 + ra) * U_DIM + cseg;
    const unsigned short* gBs = W + (size_t)(n0 + ra) * U_DIM + cseg;

#define STAGE(buf_, k_) do {                                               \
        gl2lds16(gAs + (k_),              &S.As[buf_][32 * w][0]);         \
        gl2lds16(gAs + (k_) + 16 * U_DIM, &S.As[buf_][32 * w + 16][0]);    \
        gl2lds16(gBs + (k_),              &S.Bs[buf_][32 * w][0]);         \
        gl2lds16(gBs + (k_) + 16 * U_DIM, &S.Bs[buf_][32 * w + 16][0]);    \
    } while (0)

    f4 acc[4][4] = {};

    STAGE(0, 0);                 // prologue: tile 0 in flight

#pragma unroll 2
    for (int k0 = 0; k0 < U_DIM; k0 += 32) {
        const int cur = (k0 >> 5) & 1;
        __syncthreads();         // vmcnt(0)+barrier: cur tile visible to all
                                 // waves; prev-iter reads of nxt buffer done
        if (k0 + 32 < U_DIM) STAGE(cur ^ 1, k0 + 32);  // in flight over MFMA

        bf8 af[4], bfr[4];
#pragma unroll
        for (int mt = 0; mt < 4; ++mt) {
            int row = wy * 64 + mt * 16 + cid;
            int seg = (quad + (row >> 2)) & 3;
            af[mt] = *(const bf8*)&S.As[cur][row][seg * 8];
        }
#pragma unroll
        for (int nt = 0; nt < 4; ++nt) {
            int row = wx * 64 + nt * 16 + cid;
            int seg = (quad + (row >> 2)) & 3;
            bfr[nt] = *(const bf8*)&S.Bs[cur][row][seg * 8];
        }
#pragma unroll
        for (int mt = 0; mt < 4; ++mt)
#pragma unroll
            for (int nt = 0; nt < 4; ++nt)
                acc[mt][nt] = __builtin_amdgcn_mfma_f32_16x16x32_bf16(
                    af[mt], bfr[nt], acc[mt][nt], 0, 0, 0);
    }
#undef STAGE

#pragma unroll
    for (int nt = 0; nt < 4; ++nt) {
        int col = n0 + wx * 64 + nt * 16 + cid;
        float bv = bias[col];
#pragma unroll
        for (int mt = 0; mt < 4; ++mt) {
            int rowb = m0 + wy * 64 + mt * 16 + quad * 4;
#pragma unroll
            for (int i = 0; i < 4; ++i) {
                float v = (acc[mt][nt][i] + bv) * scale;
                if constexpr (OMODE == 0) {
                    ((unsigned short*)Cv)[(size_t)(rowb + i) * U_DIM + col] = f2bf(v);
                } else if constexpr (OMODE == 1) {
                    ((float*)Cv)[(size_t)(rowb + i) * U_DIM + col] = v;
                } else {
                    // V output written directly in transposed layout:
                    // [b, s, h*64+d] -> VT[((b*H+h)*64+d)*S + s]
                    int bb = rowb >> 11;
                    int ss = (rowb & (S_LEN - 1)) + i;
                    size_t idx = ((size_t)(bb * H_NUM + (col >> 6)) * DK + (col & 63))
                                 * S_LEN + ss;
                    ((unsigned short*)Cv)[idx] = f2bf(v);
                }
            }
        }
    }
}

struct QkvArgs {
    const unsigned short* A[3];
    const unsigned short* W[3];
    const float* bias[3];
    unsigned short* C[3];
    float scale[3];
};

// XCD remap (R2, verified): each XCD owns 4 m-tiles x 8 n-tiles per z-slice.
__global__ __launch_bounds__(256, 3) void gemm_qkv(QkvArgs a) {
    __shared__ GemmLds S;
    const int L = (int)blockIdx.x + 8 * ((int)blockIdx.y + 32 * (int)blockIdx.z);
    const int xcd = L & 7, j = L >> 3;       // j in [0,96)
    const int z = j >> 5, r = j & 31;        // r in [0,32)
    const int by = xcd * 4 + (r & 3);
    const int bx = r >> 2;
    if (z == 2)
        gemm_core<2>(S, a.A[2], a.W[2], a.bias[2], a.C[2], a.scale[2], bx, by);
    else
        gemm_core<0>(S, a.A[z], a.W[z], a.bias[z], a.C[z], a.scale[z], bx, by);
}

__global__ __launch_bounds__(256, 3) void gemm_obf(
    const unsigned short* __restrict__ A, const unsigned short* __restrict__ W,
    const float* __restrict__ bias, float* __restrict__ C) {
    __shared__ GemmLds S;
    const int L = (int)blockIdx.x + 8 * (int)blockIdx.y;
    const int xcd = L & 7, j = L >> 3;       // j in [0,32)
    const int by = xcd * 4 + (j & 3);
    const int bx = j >> 2;
    gemm_core<1>(S, A, W, bias, C, 1.0f, bx, by);
}

// ---------------------------------------------------------------------------
// MFMA flash attention, R3 structure (verified): SWAPPED QK^T + IN-REGISTER
// P REDISTRIBUTION (cvt_pk + permlane32_swap + ds_swizzle), no-max softmax
// (exp2; log2e folded into Q-GEMM scale), 32 KB LDS -> 4 blocks/CU, whole
// 1024-block grid resident.  XCD-grouped remap (R2: FETCH 63->12 MB).
// ---------------------------------------------------------------------------
__global__ __launch_bounds__(256, 4) void attn_mfma(
    const unsigned short* __restrict__ Q, const unsigned short* __restrict__ K,
    const unsigned short* __restrict__ VT, unsigned short* __restrict__ O)
{
    __shared__ __align__(16) unsigned short Ks[128][64];   // also Q staging alias
    __shared__ __align__(16) unsigned short Vs[64][128];

    // ---- XCD-grouping remap (linear-ID % 8 = XCD round-robin) ----
    const int L = (int)blockIdx.x + 32 * ((int)blockIdx.y + 16 * (int)blockIdx.z);
    const int xcd = L & 7;
    const int j   = L >> 3;          // 0..127 within this XCD
    const int gl  = j & 3;           // which of this XCD's 4 (b,h) groups
    const int i   = j >> 2;          // 0..31
    const int hb  = (xcd << 2) | gl; // 0..31
    const int h = hb & 15, b = hb >> 4;
    // balanced qt permutation: {perm[x],perm[x+8],perm[x+16],perm[x+24]}
    // sums to 62 k-tiles for every x (CU-level static balance).
    const int px = i & 7, pk = i >> 3;
    const int qt = (pk == 0) ? 31 - px : (pk == 1) ? 16 + px
                 : (pk == 2) ? 15 - px : px;

    const int q0 = qt * 64;
    const int tid = threadIdx.x, w = tid >> 6, lane = tid & 63;
    const int quad = lane >> 4, cid = lane & 15;

#define KFRAG(r, s) (*(const bf8*)&Ks[r][(((s) ^ ((r) & 7)) * 8)])
#define VFRAG(r, s) (*(const bf8*)&Vs[r][(((((s) & 8) | (((s) ^ (r)) & 7))) * 8)])

    // ---- stage Q once via gl2lds16 into the Ks alias (XOR swizzle) ----
    unsigned short (*QsA)[64] = (unsigned short (*)[64])&Ks[0][0];
    const int srow8 = lane >> 3;                 // 0..7
    const int sw = ((lane & 7) ^ srow8) * 8;     // swizzled source col
    {
        const unsigned short* qg =
            Q + ((size_t)b * S_LEN + q0 + w * 16 + srow8) * U_DIM + h * DK + sw;
        gl2lds16(qg, &QsA[w * 16][0]);
        gl2lds16(qg + 8 * U_DIM, &QsA[w * 16 + 8][0]);
    }
    __syncthreads();
    const bf8 qfa = *(const bf8*)&QsA[w * 16 + cid][(((quad) ^ (cid & 7)) * 8)];
    const bf8 qfb = *(const bf8*)&QsA[w * 16 + cid][((((quad + 4)) ^ (cid & 7)) * 8)];
    // Ks overwrites happen only after iter-0's two __syncthreads -> safe.

    // ---- staging addressing ----
    const unsigned short* kgl =
        K + ((size_t)b * S_LEN + w * 32 + srow8) * U_DIM + h * DK + (lane & 7) * 8;
    const int vr0 = lane >> 4;
    const int s16 = lane & 15;
    const unsigned short* vgl =
        VT + ((size_t)(b * H_NUM + h) * DK + w * 16 + vr0) * S_LEN + s16 * 8;
    const int spE = (((s16 & 8) | ((s16 ^ vr0) & 7))) * 8;        // c even
    const int spO = (((s16 & 8) | ((s16 ^ (vr0 + 4)) & 7))) * 8;  // c odd
    const int ksw = ((lane & 7) ^ srow8) * 8;                     // K dest seg

    // named staging registers (NOT arrays — must stay in VGPRs)
    uint4 kr0, kr1, kr2, kr3, vq0, vq1, vq2, vq3;
#define PREFETCH(kt_) do {                                                    \
        const unsigned short* kp_ = kgl + (size_t)(kt_) * 128 * U_DIM;        \
        kr0 = *(const uint4*)(kp_);                                           \
        kr1 = *(const uint4*)(kp_ + (size_t)8 * U_DIM);                       \
        kr2 = *(const uint4*)(kp_ + (size_t)16 * U_DIM);                      \
        kr3 = *(const uint4*)(kp_ + (size_t)24 * U_DIM);                      \
        const unsigned short* vp_ = vgl + (kt_) * 128;                        \
        vq0 = *(const uint4*)(vp_);                                           \
        vq1 = *(const uint4*)(vp_ + (size_t)4 * S_LEN);                       \
        vq2 = *(const uint4*)(vp_ + (size_t)8 * S_LEN);                       \
        vq3 = *(const uint4*)(vp_ + (size_t)12 * S_LEN);                      \
    } while (0)

    f4 o[4] = {};
    float l_p = 0.0f;                 // per-lane partial row sum (q = cid)
    const int qrow = q0 + w * 16 + cid;

    const int nkt = (qt >> 1) + 1;   // 128-key tiles (even qt: top half masked)
    PREFETCH(0);

    for (int kt = 0; kt < nkt; ++kt) {
        __syncthreads();            // prev-iter frag reads done; LDS writable
        *(uint4*)&Ks[w * 32 + 0  + srow8][ksw] = kr0;
        *(uint4*)&Ks[w * 32 + 8  + srow8][ksw] = kr1;
        *(uint4*)&Ks[w * 32 + 16 + srow8][ksw] = kr2;
        *(uint4*)&Ks[w * 32 + 24 + srow8][ksw] = kr3;
        *(uint4*)&Vs[w * 16 + 0  + vr0][spE] = vq0;
        *(uint4*)&Vs[w * 16 + 4  + vr0][spO] = vq1;
        *(uint4*)&Vs[w * 16 + 8  + vr0][spE] = vq2;
        *(uint4*)&Vs[w * 16 + 12 + vr0][spO] = vq3;
        __syncthreads();            // tiles visible
        if (kt + 1 < nkt) PREFETCH(kt + 1);   // in flight across compute

        // ---- S^T = K Q^T over 128 keys (swapped operands).  Lane holds
        //      S[key = 16t + 4*quad + i][q = cid].  Pre-scaled by
        //      log2(e)/sqrt(DK) in the Q GEMM -> softmax uses exp2. ----
        f4 sc[8];
#pragma unroll
        for (int t = 0; t < 8; ++t) {
            int r = t * 16 + cid;
            f4 a = {};
            a = __builtin_amdgcn_mfma_f32_16x16x32_bf16(KFRAG(r, quad), qfa, a, 0, 0, 0);
            a = __builtin_amdgcn_mfma_f32_16x16x32_bf16(KFRAG(r, quad + 4), qfb, a, 0, 0, 0);
            sc[t] = a;
        }

        // ---- causal mask (last tile only; covers even-qt dead half) ----
        if (kt == nkt - 1) {
#pragma unroll
            for (int t = 0; t < 8; ++t) {
#pragma unroll
                for (int i2 = 0; i2 < 4; ++i2) {
                    int key = kt * 128 + t * 16 + quad * 4 + i2;
                    if (key > qrow) sc[t][i2] = -1e30f;
                }
            }
        }

        // ---- exp2 + per-lane partial l (single scalar: all keys, q=cid) ----
#pragma unroll
        for (int t = 0; t < 8; ++t) {
#pragma unroll
            for (int i2 = 0; i2 < 4; ++i2) {
                float p = exp2f(sc[t][i2]);
                sc[t][i2] = p;
                l_p += p;
            }
        }

        // ---- pack P to bf16 pairs: r_[t] = keys {16t+4q+0,+1},
        //      r2_[t] = keys {16t+4q+2,+3} (q = this lane's quad) ----
        unsigned int r_[8], r2_[8];
#pragma unroll
        for (int t = 0; t < 8; ++t) {
            r_[t]  = pkbf(sc[t][0], sc[t][1]);
            r2_[t] = pkbf(sc[t][2], sc[t][3]);
        }

        // ---- route pairs to PV A-frags and accumulate PV ----
        const bool qodd = (quad & 1) != 0;
#pragma unroll
        for (int f = 0; f < 4; ++f) {
            unsigned int xa = r_[2 * f], ya = r_[2 * f + 1];
            asm("v_permlane32_swap_b32 %0, %1" : "+v"(xa), "+v"(ya));
            unsigned int xas = __builtin_amdgcn_ds_swizzle((int)xa, 0x401f);
            unsigned int yas = __builtin_amdgcn_ds_swizzle((int)ya, 0x401f);
            unsigned int xb = r2_[2 * f], yb = r2_[2 * f + 1];
            asm("v_permlane32_swap_b32 %0, %1" : "+v"(xb), "+v"(yb));
            unsigned int xbs = __builtin_amdgcn_ds_swizzle((int)xb, 0x401f);
            unsigned int ybs = __builtin_amdgcn_ds_swizzle((int)yb, 0x401f);
            unsigned int u0 = qodd ? yas : xa;
            unsigned int u1 = qodd ? ybs : xb;
            unsigned int u2 = qodd ? ya : xas;
            unsigned int u3 = qodd ? yb : xbs;
            union { uint4 u; bf8 v; } pf;
            pf.u = (uint4){u0, u1, u2, u3};
#pragma unroll
            for (int t = 0; t < 4; ++t) {
                int r = t * 16 + cid;
                o[t] = __builtin_amdgcn_mfma_f32_16x16x32_bf16(
                    pf.v, VFRAG(r, 4 * f + quad), o[t], 0, 0, 0);
            }
        }
    }
#undef PREFETCH
#undef KFRAG
#undef VFRAG

    // ---- epilogue: l reduce across quads (lanes sharing cid), then
    //      redistribute inv to the o-row owners, O/l -> bf16 [b,s,u] ----
    float l = l_p;
    l += __shfl_xor(l, 16);
    l += __shfl_xor(l, 32);
    const float inv = 1.0f / l;          // valid for q-row = cid (all lanes)
#pragma unroll
    for (int i2 = 0; i2 < 4; ++i2) {
        // o rows are q = quad*4+i2; fetch inv from the lane with that cid.
        float invi = __shfl(inv, (lane & 48) | (quad * 4 + i2));
        int rowg = q0 + w * 16 + quad * 4 + i2;
        size_t rbase = ((size_t)b * S_LEN + rowg) * U_DIM + h * DK;
#pragma unroll
        for (int t = 0; t < 4; ++t)
            O[rbase + t * 16 + cid] = f2bf(o[t][i2] * invi);
    }
}

// ---------------------------------------------------------------------------
// ws layout (bf16): xq|xk|xv (8MB ea) | wq|wk|wv|wo (2MB ea) |
//                   qg|kg|vt|ao (8MB ea)  = 64 MB total.
// ---------------------------------------------------------------------------
extern "C" void kernel_launch(void* const* d_in, const int* in_sizes, int n_in,
                              void* d_out, int out_size, void* d_ws, size_t ws_size,
                              hipStream_t stream)
{
    const float* query = (const float*)d_in[0];
    const float* key   = (const float*)d_in[1];
    const float* value = (const float*)d_in[2];
    const float* Wq = (const float*)d_in[4];
    const float* bq = (const float*)d_in[5];
    const float* Wk = (const float*)d_in[6];
    const float* bk = (const float*)d_in[7];
    const float* Wv = (const float*)d_in[8];
    const float* bv = (const float*)d_in[9];
    const float* Wo = (const float*)d_in[10];
    const float* bo = (const float*)d_in[11];
    float* out = (float*)d_out;

    const size_t ACT = (size_t)M_TOT * U_DIM;
    const size_t WT  = (size_t)U_DIM * U_DIM;

    unsigned short* xq  = (unsigned short*)d_ws;
    unsigned short* xk  = xq + ACT;
    unsigned short* xv  = xk + ACT;
    unsigned short* wqb = xv + ACT;
    unsigned short* wkb = wqb + WT;
    unsigned short* wvb = wkb + WT;
    unsigned short* wob = wvb + WT;
    unsigned short* qg  = wob + WT;
    unsigned short* kg  = qg + ACT;
    unsigned short* vt  = kg + ACT;
    unsigned short* ao  = vt + ACT;

    CvtArgs ca;
    ca.src[0] = query; ca.dst[0] = xq;  ca.n[0] = (int)ACT;
    ca.src[1] = key;   ca.dst[1] = xk;  ca.n[1] = (int)ACT;
    ca.src[2] = value; ca.dst[2] = xv;  ca.n[2] = (int)ACT;
    ca.src[3] = Wq;    ca.dst[3] = wqb; ca.n[3] = (int)WT;
    ca.src[4] = Wk;    ca.dst[4] = wkb; ca.n[4] = (int)WT;
    ca.src[5] = Wv;    ca.dst[5] = wvb; ca.n[5] = (int)WT;
    ca.src[6] = Wo;    ca.dst[6] = wob; ca.n[6] = (int)WT;
    convert_bf16<<<dim3(ACT / (256 * 8), 7), 256, 0, stream>>>(ca);

    // Q scale folds softmax's 1/sqrt(DK) AND log2(e) (attn uses exp2).
    QkvArgs ga;
    ga.A[0] = xq; ga.W[0] = wqb; ga.bias[0] = bq; ga.C[0] = qg;
    ga.scale[0] = 0.125f * 1.44269504088896340736f;
    ga.A[1] = xk; ga.W[1] = wkb; ga.bias[1] = bk; ga.C[1] = kg; ga.scale[1] = 1.0f;
    ga.A[2] = xv; ga.W[2] = wvb; ga.bias[2] = bv; ga.C[2] = vt; ga.scale[2] = 1.0f;
    gemm_qkv<<<dim3(U_DIM / 128, M_TOT / 128, 3), 256, 0, stream>>>(ga);

    attn_mfma<<<dim3(S_LEN / 64, H_NUM, B_NUM), 256, 0, stream>>>(qg, kg, vt, ao);

    gemm_obf<<<dim3(U_DIM / 128, M_TOT / 128), 256, 0, stream>>>(ao, wob, bo, out);
}